// Round 1
// baseline (678.831 us; speedup 1.0000x reference)
//
#include <hip/hip_runtime.h>

// ---------------------------------------------------------------------------
// CONTEXTUAL_AUTOENCODER: B=2048, IN=9016 (att 312 | desc 512 | gpt 16x512)
// Pipeline (all GEMMs bf16 MFMA, fp32 accum, B^T weight layout):
//   q = desc@Wq+bq            (2048x512x2048)
//   kstats: dot,kn2 from gpt@Wk+bk epilogue (32768x512x2048, no k stored)
//   attn softmax -> attn_mean (16)
//   g~ = sum_v am[v]*gpt      -> fused = g~@Wv+bv  (v-GEMM eliminated)
//   z = relu([att|fused]@Wm+bm); h = relu(z@Wd1+bd1); out = h@Wd2+bd2
// ---------------------------------------------------------------------------

typedef __bf16 bf16x8 __attribute__((ext_vector_type(8)));
typedef float  f32x4  __attribute__((ext_vector_type(4)));
typedef unsigned short u16;

#define ATT   312
#define WEMB  512
#define VIEW  16
#define ADIM  2048
#define EMB   2048
#define BATCH 2048
#define INDIM 9016
#define KCAT  2360
#define KCATP 2432
#define NOUT  9016
#define NOUTP 9088

__device__ __forceinline__ u16 f2bf(float f) {
  unsigned u = __builtin_bit_cast(unsigned, f);
  u += 0x7FFFu + ((u >> 16) & 1u);            // RNE
  return (u16)(u >> 16);
}

__device__ __forceinline__ void gl_lds16(const u16* g, u16* l) {
  __builtin_amdgcn_global_load_lds((const __attribute__((address_space(1))) void*)g,
                                   (__attribute__((address_space(3))) void*)l, 16, 0, 0);
}

// --- cast x into concat-att cols, desc A-matrix, gpt A-matrix (bf16) --------
__global__ void castx_k(const float* __restrict__ x, u16* __restrict__ cc,
                        u16* __restrict__ desc, u16* __restrict__ gpt) {
  const int b = blockIdx.x, t = threadIdx.x;
  const float4* row = (const float4*)(x + (size_t)b * INDIM);
  for (int c = t; c < INDIM / 4; c += 256) {
    float4 v = row[c];
    ushort4 o = make_ushort4(f2bf(v.x), f2bf(v.y), f2bf(v.z), f2bf(v.w));
    if (c < ATT / 4)                 *(ushort4*)&cc[(size_t)b * KCATP + c * 4] = o;
    else if (c < (ATT + WEMB) / 4)   *(ushort4*)&desc[(size_t)b * WEMB + (c - ATT / 4) * 4] = o;
    else                             *(ushort4*)&gpt[(size_t)b * (VIEW * WEMB) + (c - (ATT + WEMB) / 4) * 4] = o;
  }
}

// --- transpose-cast: src[K][N] fp32 -> dst[Np][Kp] bf16 (zero padded) -------
__global__ void transcast_k(const float* __restrict__ src, u16* __restrict__ dst,
                            int K, int N, int Kp, int Np) {
  __shared__ float tile[64][65];
  const int k0 = blockIdx.y * 64, n0 = blockIdx.x * 64;
  const int t = threadIdx.x;
  const int tr = t >> 4, tc4 = (t & 15) * 4;
#pragma unroll
  for (int i = 0; i < 4; ++i) {
    const int k = k0 + tr + i * 16;
    float v0 = 0.f, v1 = 0.f, v2 = 0.f, v3 = 0.f;
    if (k < K) {
      const int n = n0 + tc4;
      const float* p = src + (size_t)k * N + n;
      if (n + 3 < N) { float4 v = *(const float4*)p; v0 = v.x; v1 = v.y; v2 = v.z; v3 = v.w; }
      else {
        if (n + 0 < N) v0 = p[0];
        if (n + 1 < N) v1 = p[1];
        if (n + 2 < N) v2 = p[2];
        if (n + 3 < N) v3 = p[3];
      }
    }
    tile[tr + i * 16][tc4 + 0] = v0;
    tile[tr + i * 16][tc4 + 1] = v1;
    tile[tr + i * 16][tc4 + 2] = v2;
    tile[tr + i * 16][tc4 + 3] = v3;
  }
  __syncthreads();
#pragma unroll
  for (int i = 0; i < 4; ++i) {
    const int rn = tr + i * 16;
    const int n = n0 + rn;
    const int kk = k0 + tc4;
    if (n < Np) {
      const bool nv = (n < N);
      ushort4 o = make_ushort4(f2bf(nv ? tile[tc4 + 0][rn] : 0.f),
                               f2bf(nv ? tile[tc4 + 1][rn] : 0.f),
                               f2bf(nv ? tile[tc4 + 2][rn] : 0.f),
                               f2bf(nv ? tile[tc4 + 3][rn] : 0.f));
      *(ushort4*)&dst[(size_t)n * Kp + kk] = o;
    }
  }
}

// --- GEMM: C[M][N] = A[M][K](bf16,rowmaj) * BT[N][K](bf16,rowmaj)^T + bias --
// MODE 0: store fp32 (col<Nreal guard). MODE 1: store bf16 (optional RELU).
// MODE 2: kstats epilogue (atomicAdd dot/kn2 per row), C not stored.
template <int MODE, bool RELU>
__global__ __launch_bounds__(256, 2)
void gemm_bt(const u16* __restrict__ A, const u16* __restrict__ BT,
             const float* __restrict__ bias, int K, int Nreal,
             float* __restrict__ dstF, u16* __restrict__ dstH, int ldc,
             const float* __restrict__ qbuf, float* __restrict__ dotb,
             float* __restrict__ kn2b) {
  __shared__ alignas(16) u16 Ash[128 * 64];
  __shared__ alignas(16) u16 Bsh[128 * 64];
  const int tid = threadIdx.x;
  const int wave = tid >> 6, lane = tid & 63;
  const long m0 = (long)blockIdx.y * 128;
  const long n0 = (long)blockIdx.x * 128;
  const int wm = wave >> 1, wn = wave & 1;
  f32x4 acc[4][4] = {};

  const int srow = (wave << 5) + (lane >> 3);  // + i*8
  const int scol = (lane & 7) << 3;

  for (int k0 = 0; k0 < K; k0 += 64) {
    __syncthreads();
#pragma unroll
    for (int i = 0; i < 4; ++i) {
      const int r = srow + i * 8;
      gl_lds16(A + (m0 + r) * (long)K + k0 + scol, &Ash[r * 64 + scol]);
      gl_lds16(BT + (n0 + r) * (long)K + k0 + scol, &Bsh[r * 64 + scol]);
    }
    __syncthreads();
#pragma unroll
    for (int kb = 0; kb < 2; ++kb) {
      bf16x8 af[4], bfv[4];
#pragma unroll
      for (int f = 0; f < 4; ++f) {
        af[f]  = *(const bf16x8*)&Ash[(wm * 64 + f * 16 + (lane & 15)) * 64 + kb * 32 + (lane >> 4) * 8];
        bfv[f] = *(const bf16x8*)&Bsh[(wn * 64 + f * 16 + (lane & 15)) * 64 + kb * 32 + (lane >> 4) * 8];
      }
#pragma unroll
      for (int mf = 0; mf < 4; ++mf)
#pragma unroll
        for (int nf = 0; nf < 4; ++nf)
          acc[mf][nf] = __builtin_amdgcn_mfma_f32_16x16x32_bf16(af[mf], bfv[nf], acc[mf][nf], 0, 0, 0);
    }
  }

  const int lr = lane >> 4, lc = lane & 15;
  if (MODE == 2) {
#pragma unroll
    for (int mf = 0; mf < 4; ++mf) {
#pragma unroll
      for (int r = 0; r < 4; ++r) {
        const long grow = m0 + wm * 64 + mf * 16 + lr * 4 + r;
        const long b = grow >> 4;
        float ds = 0.f, ks = 0.f;
#pragma unroll
        for (int nf = 0; nf < 4; ++nf) {
          const long col = n0 + wn * 64 + nf * 16 + lc;
          float kv = acc[mf][nf][r] + bias[col];
          ds += kv * qbuf[b * ADIM + col];
          ks += kv * kv;
        }
#pragma unroll
        for (int m = 1; m < 16; m <<= 1) {
          ds += __shfl_xor(ds, m, 64);
          ks += __shfl_xor(ks, m, 64);
        }
        if (lc == 0) {
          atomicAdd(&dotb[grow], ds);
          atomicAdd(&kn2b[grow], ks);
        }
      }
    }
  } else {
#pragma unroll
    for (int mf = 0; mf < 4; ++mf) {
#pragma unroll
      for (int nf = 0; nf < 4; ++nf) {
        const long col = n0 + wn * 64 + nf * 16 + lc;
        if (col < Nreal) {
          const float bv_ = bias[col];
#pragma unroll
          for (int r = 0; r < 4; ++r) {
            const long row = m0 + wm * 64 + mf * 16 + lr * 4 + r;
            float v = acc[mf][nf][r] + bv_;
            if (RELU) v = fmaxf(v, 0.f);
            if (MODE == 0) dstF[row * (long)ldc + col] = v;
            else           dstH[row * (long)ldc + col] = f2bf(v);
          }
        }
      }
    }
  }
}

// --- qn2[b] = |q[b,:]|^2 ----------------------------------------------------
__global__ void qnorm_k(const float* __restrict__ q, float* __restrict__ qn2) {
  const int b = blockIdx.x, t = threadIdx.x;
  const float4* row = (const float4*)(q + (size_t)b * ADIM);
  float s = 0.f;
#pragma unroll
  for (int i = 0; i < 2; ++i) {
    float4 v = row[t + i * 256];
    s += v.x * v.x + v.y * v.y + v.z * v.z + v.w * v.w;
  }
#pragma unroll
  for (int m = 1; m < 64; m <<= 1) s += __shfl_xor(s, m, 64);
  __shared__ float wsum[4];
  if ((t & 63) == 0) wsum[t >> 6] = s;
  __syncthreads();
  if (t == 0) qn2[b] = wsum[0] + wsum[1] + wsum[2] + wsum[3];
}

// --- per-row softmax of cs*ed, accumulate attn sums -------------------------
__global__ void attn_k(const float* __restrict__ dotb, const float* __restrict__ kn2b,
                       const float* __restrict__ qn2, float* __restrict__ asum) {
  const int b = blockIdx.x * 256 + threadIdx.x;
  const int lane = threadIdx.x & 63;
  const float q2 = qn2[b];
  const float qn = fmaxf(sqrtf(q2), 1e-8f);
  float lg[VIEW];
  float mx = -1e30f;
#pragma unroll
  for (int v = 0; v < VIEW; ++v) {
    const float d = dotb[b * VIEW + v], k2 = kn2b[b * VIEW + v];
    const float kn = fmaxf(sqrtf(k2), 1e-8f);
    const float cs = d / (qn * kn);
    const float ed = sqrtf(fmaxf(q2 - 2.f * d + k2, 0.f));
    lg[v] = cs * ed;
    mx = fmaxf(mx, lg[v]);
  }
  float s = 0.f;
#pragma unroll
  for (int v = 0; v < VIEW; ++v) { lg[v] = expf(lg[v] - mx); s += lg[v]; }
  const float inv = 1.f / s;
#pragma unroll
  for (int v = 0; v < VIEW; ++v) {
    float a = lg[v] * inv;
#pragma unroll
    for (int m = 1; m < 64; m <<= 1) a += __shfl_xor(a, m, 64);
    if (lane == 0) atomicAdd(&asum[v], a);
  }
}

// --- g~[b,w] = sum_v attn_mean[v]*gpt[b,v,w] (from fp32 x), bf16 out --------
__global__ void gtilde_k(const float* __restrict__ x, const float* __restrict__ asum,
                         u16* __restrict__ g) {
  const int b = blockIdx.x, t = threadIdx.x;  // 64 threads
  float am[VIEW];
#pragma unroll
  for (int v = 0; v < VIEW; ++v) am[v] = asum[v] * (1.f / (float)BATCH);
  const float* gx = x + (size_t)b * INDIM + (ATT + WEMB);
#pragma unroll
  for (int i = 0; i < 8; ++i) {
    const int w = i * 64 + t;
    float s = 0.f;
#pragma unroll
    for (int v = 0; v < VIEW; ++v) s += am[v] * gx[v * WEMB + w];
    g[(size_t)b * WEMB + w] = f2bf(s);
  }
}

// ---------------------------------------------------------------------------
extern "C" void kernel_launch(void* const* d_in, const int* in_sizes, int n_in,
                              void* d_out, int out_size, void* d_ws, size_t ws_size,
                              hipStream_t stream) {
  const float* x   = (const float*)d_in[0];
  const float* Wq  = (const float*)d_in[1];
  const float* bq  = (const float*)d_in[2];
  const float* Wk  = (const float*)d_in[3];
  const float* bk  = (const float*)d_in[4];
  const float* Wv  = (const float*)d_in[5];
  const float* bv  = (const float*)d_in[6];
  const float* Wm  = (const float*)d_in[7];
  const float* bm  = (const float*)d_in[8];
  const float* Wd1 = (const float*)d_in[9];
  const float* bd1 = (const float*)d_in[10];
  const float* Wd2 = (const float*)d_in[11];
  const float* bd2 = (const float*)d_in[12];
  float* out = (float*)d_out;

  char* ws = (char*)d_ws;
  size_t off = 0;
  auto alloc = [&](size_t bytes) -> void* {
    void* p = ws + off;
    off = (off + bytes + 255) & ~(size_t)255;
    return p;
  };
  u16* WqT  = (u16*)alloc((size_t)ADIM * WEMB * 2);
  u16* WkT  = (u16*)alloc((size_t)ADIM * WEMB * 2);
  u16* WvT  = (u16*)alloc((size_t)ADIM * WEMB * 2);
  u16* WmT  = (u16*)alloc((size_t)EMB * KCATP * 2);
  u16* Wd1T = (u16*)alloc((size_t)4096 * EMB * 2);
  u16* Wd2T = (u16*)alloc((size_t)NOUTP * 4096 * 2);
  u16* desc = (u16*)alloc((size_t)BATCH * WEMB * 2);
  u16* gpt  = (u16*)alloc((size_t)BATCH * VIEW * WEMB * 2);
  u16* cc   = (u16*)alloc((size_t)BATCH * KCATP * 2);
  float* q    = (float*)alloc((size_t)BATCH * ADIM * 4);
  float* qn2  = (float*)alloc((size_t)BATCH * 4);
  float* stats = (float*)alloc((size_t)(BATCH * VIEW * 2 + 64) * 4);
  float* dotb = stats;
  float* kn2b = stats + BATCH * VIEW;
  float* asum = stats + BATCH * VIEW * 2;
  u16* gt = (u16*)alloc((size_t)BATCH * WEMB * 2);
  u16* z  = (u16*)alloc((size_t)BATCH * EMB * 2);
  u16* h  = (u16*)alloc((size_t)BATCH * 4096 * 2);
  if (off > ws_size) return;  // workspace too small -> clean validation fail

  // zero: stats (dot/kn2/asum) and concat buffer (att cols + zero K-pad)
  hipMemsetAsync(stats, 0, (size_t)(BATCH * VIEW * 2 + 64) * 4, stream);
  hipMemsetAsync(cc, 0, (size_t)BATCH * KCATP * 2, stream);

  castx_k<<<BATCH, 256, 0, stream>>>(x, cc, desc, gpt);

  transcast_k<<<dim3(ADIM / 64, WEMB / 64), 256, 0, stream>>>(Wq, WqT, WEMB, ADIM, WEMB, ADIM);
  transcast_k<<<dim3(ADIM / 64, WEMB / 64), 256, 0, stream>>>(Wk, WkT, WEMB, ADIM, WEMB, ADIM);
  transcast_k<<<dim3(ADIM / 64, WEMB / 64), 256, 0, stream>>>(Wv, WvT, WEMB, ADIM, WEMB, ADIM);
  transcast_k<<<dim3(EMB / 64, KCATP / 64), 256, 0, stream>>>(Wm, WmT, KCAT, EMB, KCATP, EMB);
  transcast_k<<<dim3(4096 / 64, EMB / 64), 256, 0, stream>>>(Wd1, Wd1T, EMB, 4096, EMB, 4096);
  transcast_k<<<dim3(NOUTP / 64, 4096 / 64), 256, 0, stream>>>(Wd2, Wd2T, 4096, NOUT, 4096, NOUTP);

  // q = desc @ Wq + bq  (fp32 out)
  gemm_bt<0, false><<<dim3(ADIM / 128, BATCH / 128), 256, 0, stream>>>(
      desc, WqT, bq, WEMB, ADIM, q, nullptr, ADIM, nullptr, nullptr, nullptr);
  qnorm_k<<<BATCH, 256, 0, stream>>>(q, qn2);
  // kstats: dot/kn2 from (gpt @ Wk + bk)
  gemm_bt<2, false><<<dim3(ADIM / 128, BATCH * VIEW / 128), 256, 0, stream>>>(
      gpt, WkT, bk, WEMB, ADIM, nullptr, nullptr, 0, q, dotb, kn2b);
  attn_k<<<BATCH / 256, 256, 0, stream>>>(dotb, kn2b, qn2, asum);
  gtilde_k<<<BATCH, 64, 0, stream>>>(x, asum, gt);
  // fused = g~ @ Wv + bv -> concat cols [312, 2360)
  gemm_bt<1, false><<<dim3(ADIM / 128, BATCH / 128), 256, 0, stream>>>(
      gt, WvT, bv, WEMB, ADIM, nullptr, cc + ATT, KCATP, nullptr, nullptr, nullptr);
  // z = relu(concat @ Wm + bm)
  gemm_bt<1, true><<<dim3(EMB / 128, BATCH / 128), 256, 0, stream>>>(
      cc, WmT, bm, KCATP, EMB, nullptr, z, EMB, nullptr, nullptr, nullptr);
  // h = relu(z @ Wd1 + bd1)
  gemm_bt<1, true><<<dim3(4096 / 128, BATCH / 128), 256, 0, stream>>>(
      z, Wd1T, bd1, EMB, 4096, nullptr, h, 4096, nullptr, nullptr, nullptr);
  // out = h @ Wd2 + bd2  (fp32, guarded at 9016)
  gemm_bt<0, false><<<dim3(NOUTP / 128, BATCH / 128), 256, 0, stream>>>(
      h, Wd2T, bd2, 4096, NOUT, out, nullptr, NOUT, nullptr, nullptr, nullptr);
}